// Round 4
// baseline (104.191 us; speedup 1.0000x reference)
//
#include <hip/hip_runtime.h>
#include <string.h>

// res[i,f,h] = sum_{m,n} cgc[m,n,h] * x[i,f,m] * y[i,f,n]
// N_ATOMS=100000, N_CHAN=128, DIM_L1=3, DIM_L2=3, DIM_L3=5. All fp32.
//
// R3: LDS-staged, 1 barrier/block, 12500 blocks -> 93 us (4.4 TB/s on
// 410 MB actual HBM traffic). This version removes ALL barriers:
//  - single-wave (64-thread) persistent blocks, 13/CU (12 KB LDS each)
//  - each wave double-buffers its OWN 256-pair tile via global_load_lds
//    and synchronizes only with counted s_waitcnt vmcnt(N) (T3/T4):
//      prologue: issue loads(t0) -> buf0, vmcnt(0)
//      loop:     ds_read frags(t) | issue loads(t+1) -> buf^1 | compute
//                | stage outs -> LDS | coalesced nt-store | vmcnt(5)
//    (outstanding at loop bottom: loads(t+1) x6 then stores(t) x5;
//     vmcnt(5) retires exactly the 6 loads of tile t+1)
//  - all LDS traffic is same-wave (in-order DS pipe) -> no sync needed.

constexpr int N_PAIRS    = 100000 * 128;          // 12,800,000
constexpr int WAVE_PAIRS = 256;                   // pairs per wave-tile
constexpr int NT         = N_PAIRS / WAVE_PAIRS;  // 50,000 tiles (exact)
constexpr int NB         = 3328;                  // 13 blocks/CU * 256 CU

typedef float vf4 __attribute__((ext_vector_type(4)));

__global__ __launch_bounds__(64) void tp_contract_kernel(
    const float* __restrict__ x,
    const float* __restrict__ y,
    const float* __restrict__ cgc,
    float* __restrict__ out)
{
    // per-buffer: x chunk f4[0..192) + y chunk f4[192..384) = 6 KB; double = 12 KB
    __shared__ float4 smem[2][384];

    const int lane = threadIdx.x;     // 0..63 (single wave)

    // cgc: 45 floats, uniform address -> SGPRs
    float c[3][3][5];
#pragma unroll
    for (int m = 0; m < 3; ++m)
#pragma unroll
        for (int n = 0; n < 3; ++n)
#pragma unroll
            for (int h = 0; h < 5; ++h)
                c[m][n][h] = cgc[(m * 3 + n) * 5 + h];

    const float4* gx4 = reinterpret_cast<const float4*>(x);
    const float4* gy4 = reinterpret_cast<const float4*>(y);

#define ISSUE_TILE(tile, buf)                                                      \
    do {                                                                           \
        const float4* _gx = gx4 + (size_t)(tile) * 192;                            \
        const float4* _gy = gy4 + (size_t)(tile) * 192;                            \
        _Pragma("unroll")                                                          \
        for (int j = 0; j < 3; ++j) {                                              \
            __builtin_amdgcn_global_load_lds(                                      \
                (const __attribute__((address_space(1))) void*)(_gx + j * 64 + lane), \
                (__attribute__((address_space(3))) void*)(&smem[buf][j * 64]),     \
                16, 0, 0);                                                         \
            __builtin_amdgcn_global_load_lds(                                      \
                (const __attribute__((address_space(1))) void*)(_gy + j * 64 + lane), \
                (__attribute__((address_space(3))) void*)(&smem[buf][192 + j * 64]), \
                16, 0, 0);                                                         \
        }                                                                          \
    } while (0)

    int t = blockIdx.x;               // first tile for this wave (NB < NT always)
    int b = 0;

    ISSUE_TILE(t, 0);
    asm volatile("s_waitcnt vmcnt(0)" ::: "memory");
    __builtin_amdgcn_sched_barrier(0);

    while (true) {
        // ---- per-thread fragments from own buffer (same-wave DS, in order) ----
        float4 xv0 = smem[b][lane * 3 + 0];
        float4 xv1 = smem[b][lane * 3 + 1];
        float4 xv2 = smem[b][lane * 3 + 2];
        float4 yv0 = smem[b][192 + lane * 3 + 0];
        float4 yv1 = smem[b][192 + lane * 3 + 1];
        float4 yv2 = smem[b][192 + lane * 3 + 2];

        // ---- prefetch next tile into other buffer (overlaps compute+store) ----
        const int tn = t + NB;
        const bool has_next = (tn < NT);
        if (has_next) ISSUE_TILE(tn, b ^ 1);

        float xs[12] = { xv0.x, xv0.y, xv0.z, xv0.w,
                         xv1.x, xv1.y, xv1.z, xv1.w,
                         xv2.x, xv2.y, xv2.z, xv2.w };
        float ys[12] = { yv0.x, yv0.y, yv0.z, yv0.w,
                         yv1.x, yv1.y, yv1.z, yv1.w,
                         yv2.x, yv2.y, yv2.z, yv2.w };

        float o[20];
#pragma unroll
        for (int p = 0; p < 4; ++p) {
            float acc[5] = {0.f, 0.f, 0.f, 0.f, 0.f};
#pragma unroll
            for (int m = 0; m < 3; ++m) {
#pragma unroll
                for (int n = 0; n < 3; ++n) {
                    const float xy = xs[p * 3 + m] * ys[p * 3 + n];
#pragma unroll
                    for (int h = 0; h < 5; ++h)
                        acc[h] = fmaf(c[m][n][h], xy, acc[h]);
                }
            }
#pragma unroll
            for (int h = 0; h < 5; ++h) o[p * 5 + h] = acc[h];
        }

        // ---- stage outputs into own (consumed) buffer: same-wave in-order DS ----
        // write idx 5*lane+q (80B lane stride: each 8-lane group covers all 32 banks)
#pragma unroll
        for (int q = 0; q < 5; ++q)
            smem[b][lane * 5 + q] = make_float4(o[q * 4 + 0], o[q * 4 + 1],
                                                o[q * 4 + 2], o[q * 4 + 3]);

        // ---- coalesced non-temporal stores (lane stride 16 B) ----
        float4* go = reinterpret_cast<float4*>(out) + (size_t)t * 320;
#pragma unroll
        for (int j = 0; j < 5; ++j) {
            float4 v = smem[b][j * 64 + lane];
            vf4 vv;
            memcpy(&vv, &v, 16);
            __builtin_nontemporal_store(vv, reinterpret_cast<vf4*>(&go[j * 64 + lane]));
        }

        if (!has_next) break;
        t = tn;
        b ^= 1;
        // outstanding (issue order): loads(t) x6, stores(prev) x5.
        // vmcnt(5) retires the 6 oldest = all loads of the tile we read next.
        asm volatile("s_waitcnt vmcnt(5)" ::: "memory");
        __builtin_amdgcn_sched_barrier(0);
    }
#undef ISSUE_TILE
}

extern "C" void kernel_launch(void* const* d_in, const int* in_sizes, int n_in,
                              void* d_out, int out_size, void* d_ws, size_t ws_size,
                              hipStream_t stream) {
    const float* x   = (const float*)d_in[0];
    const float* y   = (const float*)d_in[1];
    const float* cgc = (const float*)d_in[2];
    float* out = (float*)d_out;

    tp_contract_kernel<<<NB, 64, 0, stream>>>(x, y, cgc, out);
}

// Round 6
// 92.622 us; speedup vs baseline: 1.1249x; 1.1249x over previous
//
#include <hip/hip_runtime.h>
#include <string.h>

// res[i,f,h] = sum_{m,n} cgc[m,n,h] * x[i,f,m] * y[i,f,n]
// N_ATOMS=100000, N_CHAN=128, DIM_L1=3, DIM_L2=3, DIM_L3=5. All fp32.
//
// R3 (1024-pair tiles, 24 KB LDS, 1 barrier): 93.3 us, 57% occ.
// R5 (512-pair tiles) FAILED: phase-4 store was block-linear, so waves
// read OTHER waves' staged outputs with no barrier -> race.
// R6 = R5 with phase 4 made wave-private again: wave w stores its own
// 160 float4 (rounds 64/64/32), lane-contiguous 16B/lane. One barrier,
// zero cross-wave LDS dependencies after it.
// 12 KB LDS -> 8 blocks/CU = 32 waves/CU nominal; 25,000 blocks.

constexpr int N_PAIRS = 100000 * 128;              // 12,800,000
constexpr int PAIRS_PER_BLOCK = 512;               // 256 threads * 2 pairs
constexpr int NBLOCKS = N_PAIRS / PAIRS_PER_BLOCK; // 25,000 exact, no tail

typedef float vf4 __attribute__((ext_vector_type(4)));

__global__ __launch_bounds__(256) void tp_contract_kernel(
    const float* __restrict__ x,
    const float* __restrict__ y,
    const float* __restrict__ cgc,
    float* __restrict__ out)
{
    // 12 KB: x tile f4[0,384) | y tile f4[384,768). Out staging reuses
    // each wave's own consumed chunks (same-wave in-order DS pipe).
    __shared__ float4 smem4[768];
    float2* smem2 = reinterpret_cast<float2*>(smem4);

    const int tid  = threadIdx.x;
    const int lane = tid & 63;
    const int w    = tid >> 6;          // wave id 0..3
    const size_t blk = blockIdx.x;

    // cgc: 45 floats, uniform address -> SGPRs
    float c[3][3][5];
#pragma unroll
    for (int m = 0; m < 3; ++m)
#pragma unroll
        for (int n = 0; n < 3; ++n)
#pragma unroll
            for (int h = 0; h < 5; ++h)
                c[m][n][h] = cgc[(m * 3 + n) * 5 + h];

    // ---- phase 1: global -> LDS DMA, 3 rounds x 256 lanes ----
    // round r, wave w covers f4 idx [r*256 + w*64, +64): always inside one
    // region (region boundary 384 is a multiple of 64). Wave-uniform base.
    const float4* gx4 = reinterpret_cast<const float4*>(x) + blk * 384;
    const float4* gy4 = reinterpret_cast<const float4*>(y) + blk * 384;
#pragma unroll
    for (int r = 0; r < 3; ++r) {
        const int idx0 = r * 256 + w * 64;
        const float4* src = (idx0 < 384) ? (gx4 + idx0) : (gy4 + (idx0 - 384));
        __builtin_amdgcn_global_load_lds(
            (const __attribute__((address_space(1))) void*)(src + lane),
            (__attribute__((address_space(3))) void*)(&smem4[idx0]),
            16, 0, 0);
    }
    __syncthreads();   // the ONLY barrier

    // ---- phase 2: per-thread fragments (2 pairs): x floats [6t, 6t+6) ----
    // float2 reads, 24B lane stride: 2-way bank aliasing = free.
    float2 xa = smem2[3 * tid + 0];
    float2 xb = smem2[3 * tid + 1];
    float2 xc = smem2[3 * tid + 2];
    float2 ya = smem2[768 + 3 * tid + 0];
    float2 yb = smem2[768 + 3 * tid + 1];
    float2 yc = smem2[768 + 3 * tid + 2];

    float xs[6] = { xa.x, xa.y, xb.x, xb.y, xc.x, xc.y };
    float ys[6] = { ya.x, ya.y, yb.x, yb.y, yc.x, yc.y };

    float o[10];
#pragma unroll
    for (int p = 0; p < 2; ++p) {
        float acc[5] = {0.f, 0.f, 0.f, 0.f, 0.f};
#pragma unroll
        for (int m = 0; m < 3; ++m) {
#pragma unroll
            for (int n = 0; n < 3; ++n) {
                const float xy = xs[p * 3 + m] * ys[p * 3 + n];
#pragma unroll
                for (int h = 0; h < 5; ++h)
                    acc[h] = fmaf(c[m][n][h], xy, acc[h]);
            }
        }
#pragma unroll
        for (int h = 0; h < 5; ++h) o[p * 5 + h] = acc[h];
    }

    // ---- phase 3: wave-private out staging (no barrier) ----
    // in-wave out float2 index u = 5*lane + q in [0,320):
    //   u < 192 -> wave's x chunk  smem2[192*w + u]
    //   u >=192 -> wave's y chunk  smem2[768 + 192*w + (u-192)]
    // Same-wave DS ops are in-order; writes depend on this wave's own
    // phase-2 reads, and no other wave touches these chunks again.
#pragma unroll
    for (int q = 0; q < 5; ++q) {
        const int u = lane * 5 + q;
        const int a = (u < 192) ? (192 * w + u) : (768 + 192 * w + (u - 192));
        smem2[a] = make_float2(o[2 * q], o[2 * q + 1]);
    }

    // ---- phase 4: wave-private coalesced nt-stores (rounds 64/64/32) ----
    // wave w owns block-out f4 range [160*w, 160*w + 160):
    //   in-wave f4 offset o4: o4 < 96 -> smem4[96*w + o4]
    //                         o4 >=96 -> smem4[384 + 96*w + (o4 - 96)]
    float4* go = reinterpret_cast<float4*>(out) + blk * 640 + (size_t)w * 160;
#pragma unroll
    for (int j = 0; j < 3; ++j) {
        const int o4 = j * 64 + lane;
        if (j < 2 || lane < 32) {
            const int a4 = (o4 < 96) ? (96 * w + o4)
                                     : (384 + 96 * w + (o4 - 96));
            float4 val = smem4[a4];
            vf4 vv;
            memcpy(&vv, &val, 16);
            __builtin_nontemporal_store(vv, reinterpret_cast<vf4*>(&go[o4]));
        }
    }
}

extern "C" void kernel_launch(void* const* d_in, const int* in_sizes, int n_in,
                              void* d_out, int out_size, void* d_ws, size_t ws_size,
                              hipStream_t stream) {
    const float* x   = (const float*)d_in[0];
    const float* y   = (const float*)d_in[1];
    const float* cgc = (const float*)d_in[2];
    float* out = (float*)d_out;

    tp_contract_kernel<<<NBLOCKS, 256, 0, stream>>>(x, y, cgc, out);
}